// Round 1
// baseline (132.530 us; speedup 1.0000x reference)
//
#include <hip/hip_runtime.h>

#define Bn 16
#define Hn 128
#define Wn 8192
#define NMAX 64

// Grid layout: x = 96 blocks per batch (64 segment-copy + 32 zero-tail), y = batch.
#define SEG_BLKS 64
#define ZERO_BLKS 32                 // each zeroes Hn/ZERO_BLKS = 4 rows
#define BLKS_PER_B (SEG_BLKS + ZERO_BLKS)
#define ROWS_PER_ZB (Hn / ZERO_BLKS)

typedef float nt_f4 __attribute__((ext_vector_type(4)));  // native vec for nontemporal builtin

// =====================================================================
// R10: rectangle-copy restructure (replaces R8 LDS row-image kernel).
// Evidence: rocprof top-5 are all harness poison-fills (2x ~45us, 268MB
// each) -> our kernel is ~26us of the 116us total vs a 14.2us memory
// floor (25MB read + 64MB write @ 6.3TB/s). The 1.8x gap was structural:
// 32KB LDS image (4 blocks/CU occupancy cap), global->LDS->global double
// handling with a full-block barrier, and a per-ROW metadata scan that is
// really per-BATCH.
// New shape: block (b, seg) copies the 128-row x (w+1) rectangle straight
// global->global; block (b, 64+z) streams the shared per-batch zero tail
// as aligned nontemporal float4. No LDS, no __syncthreads, scan redone
// redundantly per wave (512B read + 6 shfl_up = trivial), per-seg values
// broadcast via __shfl. 1536 light blocks -> high occupancy + MLP.
// =====================================================================
__global__ __launch_bounds__(256) void pack_rect_kernel(
    const float* __restrict__ x, const int* __restrict__ xi,
    const int* __restrict__ N, const float* __restrict__ sep_param,
    float* __restrict__ out, float* __restrict__ out_xi) {
    const int b    = blockIdx.y;
    const int k    = blockIdx.x;
    const int tid  = threadIdx.x;
    const int lane = tid & 63;
    const int wave = tid >> 6;

    // ---- per-wave redundant 64-lane width scan (no LDS, no barrier) ----
    const int nb = N[b];
    const int s0 = xi[(b * NMAX + lane) * 2 + 0];
    const int s1 = xi[(b * NMAX + lane) * 2 + 1];
    int w = s1 - s0; if (w < 0) w = 0;
    const bool valid = lane < nb;
    const int wv = valid ? w : 0;
    int c = wv;
    #pragma unroll
    for (int d = 1; d < 64; d <<= 1) {
        int t = __shfl_up(c, d, 64);
        if (lane >= d) c += t;
    }
    const int start_new = c - wv + lane;   // csum - wv + idx
    const int end_new   = c + lane;        // csum + idx

    // ---- fused xi_new emit: one writer block per batch (k==0, wave 0) ----
    if (k == 0 && wave == 0) {
        out_xi[(b * NMAX + lane) * 2 + 0] = valid ? (float)start_new : 0.0f;
        out_xi[(b * NMAX + lane) * 2 + 1] = valid ? (float)end_new   : 0.0f;
    }

    const float sep = sep_param[0];
    float* __restrict__ ob = out + (size_t)b * Hn * Wn;

    if (k < SEG_BLKS) {
        // ================= segment rectangle copy =================
        const int seg = k;
        if (seg >= nb) return;
        const int seg_s = __shfl(start_new, seg);
        const int seg_w = __shfl(wv, seg);
        const int seg_a = __shfl(s0, seg);
        const int wtot  = seg_w + ((seg < nb - 1) ? 1 : 0);  // +1 sep col except last
        const float* __restrict__ xb = x + (size_t)b * Hn * Wn;

        for (int c0 = 0; c0 < wtot; c0 += 64) {
            const int col = c0 + lane;
            if (col < wtot) {
                const bool is_data = col < seg_w;       // else: sep token column
                const int  src     = seg_a + col;
                const int  dst     = seg_s + col;
                // 32 rows per thread (r = wave + 4*i), 8-deep load/store pipeline
                for (int rr = 0; rr < 32; rr += 8) {
                    float v[8];
                    #pragma unroll
                    for (int i = 0; i < 8; ++i) {
                        const int r = wave + 4 * (rr + i);
                        v[i] = is_data ? xb[(size_t)r * Wn + src] : sep;
                    }
                    #pragma unroll
                    for (int i = 0; i < 8; ++i) {
                        const int r = wave + 4 * (rr + i);
                        __builtin_nontemporal_store(v[i], &ob[(size_t)r * Wn + dst]);
                    }
                }
            }
        }
    } else {
        // ================= zero tail [tail, Wn) for 4 rows =================
        const int tail = (nb > 0) ? __shfl(end_new, nb - 1) : 0;
        const int t4   = (tail + 3) & ~3;        // round up to float4 alignment
        const int r0   = (k - SEG_BLKS) * ROWS_PER_ZB;
        const nt_f4 z4 = {0.0f, 0.0f, 0.0f, 0.0f};
        for (int r = r0; r < r0 + ROWS_PER_ZB; ++r) {
            float* __restrict__ orow = ob + (size_t)r * Wn;
            if (tid < (t4 - tail))               // <=3 scalar stores to alignment
                __builtin_nontemporal_store(0.0f, &orow[tail + tid]);
            nt_f4* orow4 = reinterpret_cast<nt_f4*>(orow);
            for (int i4 = (t4 >> 2) + tid; i4 < (Wn >> 2); i4 += 256) {
                __builtin_nontemporal_store(z4, &orow4[i4]);
            }
        }
    }
}

extern "C" void kernel_launch(void* const* d_in, const int* in_sizes, int n_in,
                              void* d_out, int out_size, void* d_ws, size_t ws_size,
                              hipStream_t stream) {
    const float* x   = (const float*)d_in[0];
    const int* xi    = (const int*)d_in[1];
    const int* N     = (const int*)d_in[2];
    const float* sep = (const float*)d_in[3];

    float* out_x  = (float*)d_out;
    float* out_xi = (float*)d_out + (size_t)Bn * Hn * Wn;

    dim3 grid(BLKS_PER_B, Bn);
    pack_rect_kernel<<<grid, 256, 0, stream>>>(x, xi, N, sep, out_x, out_xi);
}

// Round 2
// 128.071 us; speedup vs baseline: 1.0348x; 1.0348x over previous
//
#include <hip/hip_runtime.h>

#define Bn 16
#define Hn 128
#define Wn 8192
#define NMAX 64

// Grid layout: x = 96 blocks per batch (64 segment-copy + 32 zero-tail), y = batch.
#define SEG_BLKS 64
#define ZERO_BLKS 32                 // each zeroes Hn/ZERO_BLKS = 4 rows
#define BLKS_PER_B (SEG_BLKS + ZERO_BLKS)
#define ROWS_PER_ZB (Hn / ZERO_BLKS)

typedef float nt_f4 __attribute__((ext_vector_type(4)));  // native vec for nontemporal builtin

// =====================================================================
// R11: rect-copy with FULL-DEPTH load issue (fixes R10 regression).
// R10 post-mortem: seg-copy ran 2.1 TB/s (26% peak) NOT because of
// traffic (FETCH 19.2MB / WRITE 71MB are near-ideal) but because the
// 8-deep load/store pipeline capped MLP at 8 outstanding loads/wave:
// 24 waves/CU x 8 x 4B / ~900cy HBM latency = ~550 GB/s read -> 35us on
// 19MB of reads. Latency-bound, not BW-bound.
// Fix: issue ALL 32 row-loads per thread (v[32], fully unrolled, static
// indices -> registers) before the store burst, like R8's PASS 1 did.
// MLP 8 -> 32 = ~4x read throughput. Everything else kept from R10:
// no LDS, no barriers, per-wave redundant scan, per-batch zero tail as
// aligned nontemporal float4 full-line streams.
// =====================================================================
__global__ __launch_bounds__(256) void pack_rect_kernel(
    const float* __restrict__ x, const int* __restrict__ xi,
    const int* __restrict__ N, const float* __restrict__ sep_param,
    float* __restrict__ out, float* __restrict__ out_xi) {
    const int b    = blockIdx.y;
    const int k    = blockIdx.x;
    const int tid  = threadIdx.x;
    const int lane = tid & 63;
    const int wave = tid >> 6;

    // ---- per-wave redundant 64-lane width scan (no LDS, no barrier) ----
    const int nb = N[b];
    const int s0 = xi[(b * NMAX + lane) * 2 + 0];
    const int s1 = xi[(b * NMAX + lane) * 2 + 1];
    int w = s1 - s0; if (w < 0) w = 0;
    const bool valid = lane < nb;
    const int wv = valid ? w : 0;
    int c = wv;
    #pragma unroll
    for (int d = 1; d < 64; d <<= 1) {
        int t = __shfl_up(c, d, 64);
        if (lane >= d) c += t;
    }
    const int start_new = c - wv + lane;   // csum - wv + idx
    const int end_new   = c + lane;        // csum + idx

    // ---- fused xi_new emit: one writer block per batch (k==0, wave 0) ----
    if (k == 0 && wave == 0) {
        out_xi[(b * NMAX + lane) * 2 + 0] = valid ? (float)start_new : 0.0f;
        out_xi[(b * NMAX + lane) * 2 + 1] = valid ? (float)end_new   : 0.0f;
    }

    const float sep = sep_param[0];
    float* __restrict__ ob = out + (size_t)b * Hn * Wn;

    if (k < SEG_BLKS) {
        // ================= segment rectangle copy =================
        const int seg = k;
        if (seg >= nb) return;
        const int seg_s = __shfl(start_new, seg);
        const int seg_w = __shfl(wv, seg);
        const int seg_a = __shfl(s0, seg);
        const int wtot  = seg_w + ((seg < nb - 1) ? 1 : 0);  // +1 sep col except last
        const float* __restrict__ xb = x + (size_t)b * Hn * Wn;

        for (int c0 = 0; c0 < wtot; c0 += 64) {
            const int col     = c0 + lane;
            const bool act    = col < wtot;
            const bool is_data = col < seg_w;        // else: sep token column
            const int  src    = seg_a + col;
            const int  dst    = seg_s + col;

            // ---- PASS 1: issue ALL 32 row loads (MLP=32, predicated) ----
            float v[32];
            #pragma unroll
            for (int i = 0; i < 32; ++i) {
                const int r = wave + 4 * i;
                v[i] = is_data ? xb[(size_t)r * Wn + src] : sep;
            }
            // ---- PASS 2: store burst (compiler interleaves vmcnt) ----
            if (act) {
                #pragma unroll
                for (int i = 0; i < 32; ++i) {
                    const int r = wave + 4 * i;
                    __builtin_nontemporal_store(v[i], &ob[(size_t)r * Wn + dst]);
                }
            }
        }
    } else {
        // ================= zero tail [tail, Wn) for 4 rows =================
        const int tail = (nb > 0) ? __shfl(end_new, nb - 1) : 0;
        const int t4   = (tail + 3) & ~3;        // round up to float4 alignment
        const int r0   = (k - SEG_BLKS) * ROWS_PER_ZB;
        const nt_f4 z4 = {0.0f, 0.0f, 0.0f, 0.0f};
        for (int r = r0; r < r0 + ROWS_PER_ZB; ++r) {
            float* __restrict__ orow = ob + (size_t)r * Wn;
            if (tid < (t4 - tail))               // <=3 scalar stores to alignment
                __builtin_nontemporal_store(0.0f, &orow[tail + tid]);
            nt_f4* orow4 = reinterpret_cast<nt_f4*>(orow);
            for (int i4 = (t4 >> 2) + tid; i4 < (Wn >> 2); i4 += 256) {
                __builtin_nontemporal_store(z4, &orow4[i4]);
            }
        }
    }
}

extern "C" void kernel_launch(void* const* d_in, const int* in_sizes, int n_in,
                              void* d_out, int out_size, void* d_ws, size_t ws_size,
                              hipStream_t stream) {
    const float* x   = (const float*)d_in[0];
    const int* xi    = (const int*)d_in[1];
    const int* N     = (const int*)d_in[2];
    const float* sep = (const float*)d_in[3];

    float* out_x  = (float*)d_out;
    float* out_xi = (float*)d_out + (size_t)Bn * Hn * Wn;

    dim3 grid(BLKS_PER_B, Bn);
    pack_rect_kernel<<<grid, 256, 0, stream>>>(x, xi, N, sep, out_x, out_xi);
}

// Round 3
// 127.505 us; speedup vs baseline: 1.0394x; 1.0044x over previous
//
#include <hip/hip_runtime.h>

#define Bn 16
#define Hn 128
#define Wn 8192
#define NMAX 64

#define TILE 256               // output columns per column-tile
#define RPB 32                 // rows per block
#define CT (Wn / TILE)         // 32 column tiles
#define RB (Hn / RPB)          // 4 row blocks per column tile

typedef float nt_f4 __attribute__((ext_vector_type(4)));  // native vec for nontemporal builtin

// =====================================================================
// R12: uniform output-tile gather (replaces R10/R11 per-segment scatter).
// R11 post-mortem: seg-grid was 1536 NON-UNIFORM blocks -> measured
// occupancy 27% (~9 waves/CU avg: instant-exit blocks, early-finishing
// zero blocks, width stragglers). Kernel ~40us vs 14.2us floor; raising
// per-wave MLP 8->32 bought only 4us -> the binding constraint is
// AVERAGE OCCUPANCY x in-flight, not per-wave depth.
// New shape: one block per OUTPUT tile (16b x 32 coltiles x 4 rowblks =
// 2048 identical blocks, 8/CU, LDS=0). Thread owns 4 consecutive cols x
// 8 rows. Column->segment mapping via 6-step in-register binary search
// over the wave-held sorted start_new[] (__shfl = ds_bpermute), i.e. the
// reference's searchsorted. Data cols gather (MLP=32), sep cols fill
// sep, beyond-tail cols fill 0 -- all in ONE uniform code path, so every
// block writes exactly 32KB as aligned nontemporal float4 (same store
// shape as the 6.2 TB/s harness fills).
// =====================================================================
__global__ __launch_bounds__(256) void pack_tile_kernel(
    const float* __restrict__ x, const int* __restrict__ xi,
    const int* __restrict__ N, const float* __restrict__ sep_param,
    float* __restrict__ out, float* __restrict__ out_xi) {
    const int b    = blockIdx.y;
    const int tb   = blockIdx.x;          // 0..127
    const int tile = tb & (CT - 1);       // 0..31 column tile
    const int rblk = tb >> 5;             // 0..3  row block
    const int tid  = threadIdx.x;
    const int lane = tid & 63;
    const int wave = tid >> 6;

    // ---- per-wave redundant 64-lane width scan (no LDS, no barrier) ----
    const int nb = N[b];
    const int s0 = xi[(b * NMAX + lane) * 2 + 0];
    const int s1 = xi[(b * NMAX + lane) * 2 + 1];
    int w = s1 - s0; if (w < 0) w = 0;
    const int wv = (lane < nb) ? w : 0;
    int c = wv;
    #pragma unroll
    for (int d = 1; d < 64; d <<= 1) {
        int t = __shfl_up(c, d, 64);
        if (lane >= d) c += t;
    }
    const int start_new = c - wv + lane;   // sorted, strictly increasing
    const int end_new   = c + lane;

    // ---- fused xi_new emit: one writer block per batch ----
    if (tb == 0 && wave == 0) {
        const bool valid = lane < nb;
        out_xi[(b * NMAX + lane) * 2 + 0] = valid ? (float)start_new : 0.0f;
        out_xi[(b * NMAX + lane) * 2 + 1] = valid ? (float)end_new   : 0.0f;
    }

    const float sep = sep_param[0];

    // ---- per-column segment lookup: binary search via ds_bpermute ----
    const int cbase = tile * TILE + lane * 4;      // 16B-aligned col group
    int  srcc[4];
    float fillv[4];
    bool isdat[4];
    #pragma unroll
    for (int q = 0; q < 4; ++q) {
        const int j = cbase + q;
        int lo = 0;                                 // invariant: start_new[lo] <= j
        #pragma unroll
        for (int s = 32; s >= 1; s >>= 1) {
            const int mid = lo + s;
            const int sm = __shfl(start_new, mid & 63);
            if (mid < NMAX && sm <= j) lo = mid;
        }
        const int st  = __shfl(start_new, lo);
        const int wd  = __shfl(wv, lo);
        const int sc  = __shfl(s0, lo);
        const int off = j - st;
        isdat[q] = off < wd;                        // data column
        const bool issep = (off == wd) && (lo < nb - 1);  // sep token column
        srcc[q]  = sc + off;
        fillv[q] = issep ? sep : 0.0f;              // sep or beyond-tail zero
    }

    // ---- gather 8 rows x 4 cols (32 predicated loads, MLP=32) ----
    const int rbase = rblk * RPB + wave * 8;
    const float* __restrict__ xb = x + (size_t)b * Hn * Wn;
    float* __restrict__ ob = out + (size_t)b * Hn * Wn + cbase;

    float4 v[8];
    #pragma unroll
    for (int i = 0; i < 8; ++i) {
        const float* __restrict__ rp = xb + (size_t)(rbase + i) * Wn;
        v[i].x = isdat[0] ? rp[srcc[0]] : fillv[0];
        v[i].y = isdat[1] ? rp[srcc[1]] : fillv[1];
        v[i].z = isdat[2] ? rp[srcc[2]] : fillv[2];
        v[i].w = isdat[3] ? rp[srcc[3]] : fillv[3];
    }
    // ---- 8 aligned nontemporal float4 stores (1KB/wave-instr) ----
    #pragma unroll
    for (int i = 0; i < 8; ++i) {
        nt_f4 t = {v[i].x, v[i].y, v[i].z, v[i].w};
        __builtin_nontemporal_store(t, (nt_f4*)(ob + (size_t)(rbase + i) * Wn));
    }
}

extern "C" void kernel_launch(void* const* d_in, const int* in_sizes, int n_in,
                              void* d_out, int out_size, void* d_ws, size_t ws_size,
                              hipStream_t stream) {
    const float* x   = (const float*)d_in[0];
    const int* xi    = (const int*)d_in[1];
    const int* N     = (const int*)d_in[2];
    const float* sep = (const float*)d_in[3];

    float* out_x  = (float*)d_out;
    float* out_xi = (float*)d_out + (size_t)Bn * Hn * Wn;

    dim3 grid(CT * RB, Bn);   // 128 x 16 = 2048 uniform blocks
    pack_tile_kernel<<<grid, 256, 0, stream>>>(x, xi, N, sep, out_x, out_xi);
}

// Round 4
// 120.901 us; speedup vs baseline: 1.0962x; 1.0546x over previous
//
#include <hip/hip_runtime.h>

#define Bn 16
#define Hn 128
#define Wn 8192
#define NMAX 64

#define TILE 256               // output columns per column-tile
#define RPB 32                 // rows per block
#define CT (Wn / TILE)         // 32 column tiles
#define RB (Hn / RPB)          // 4 row blocks per column tile

// =====================================================================
// R13: uniform tile gather, CACHED stores + contiguous lane ownership.
// R12 post-mortem: three structurally different kernels (R10/R11/R12:
// scatter, deep-MLP scatter, uniform gather) ALL plateau at 39-44us
// (~2.2 TB/s) and R8 at 28us (3.2 TB/s) -- occupancy, MLP, and grid
// uniformity are each ruled out as the binding constraint. The common
// factor vs the 6.1 TB/s harness fills and the 6.3 TB/s copy ubench:
// every previous kernel used __builtin_nontemporal_store for the whole
// 64-71MB output, forcing all writes to HBM inside the measured window.
// The output FITS IN L3 (64MB << 256MB): with plain cached stores the
// writes retire at L2/L3 rate, and the dirty lines are overwritten
// in-cache by the next iteration's poison fill -- they never need HBM.
// Change 1 (H5): drop nontemporal everywhere -> plain stores.
// Change 2 (H1): lane owns cols {base + q*64 + lane}, q=0..3, so every
// gather load AND every store is a 64-lane 4B-contiguous (256B) access
// (R8's proven load shape), instead of R12's 16B-strided lanes (1KB
// span, 25% utilization per instruction).
// Prediction: kernel 39.5 -> ~14-18us (H5) / ~32us (H1 only).
// =====================================================================
__global__ __launch_bounds__(256) void pack_tile_kernel(
    const float* __restrict__ x, const int* __restrict__ xi,
    const int* __restrict__ N, const float* __restrict__ sep_param,
    float* __restrict__ out, float* __restrict__ out_xi) {
    const int b    = blockIdx.y;
    const int tb   = blockIdx.x;          // 0..127
    const int tile = tb & (CT - 1);       // 0..31 column tile
    const int rblk = tb >> 5;             // 0..3  row block
    const int tid  = threadIdx.x;
    const int lane = tid & 63;
    const int wave = tid >> 6;

    // ---- per-wave redundant 64-lane width scan (no LDS, no barrier) ----
    const int nb = N[b];
    const int s0 = xi[(b * NMAX + lane) * 2 + 0];
    const int s1 = xi[(b * NMAX + lane) * 2 + 1];
    int w = s1 - s0; if (w < 0) w = 0;
    const int wv = (lane < nb) ? w : 0;
    int c = wv;
    #pragma unroll
    for (int d = 1; d < 64; d <<= 1) {
        int t = __shfl_up(c, d, 64);
        if (lane >= d) c += t;
    }
    const int start_new = c - wv + lane;   // sorted, strictly increasing
    const int end_new   = c + lane;

    // ---- fused xi_new emit: one writer block per batch ----
    if (tb == 0 && wave == 0) {
        const bool valid = lane < nb;
        out_xi[(b * NMAX + lane) * 2 + 0] = valid ? (float)start_new : 0.0f;
        out_xi[(b * NMAX + lane) * 2 + 1] = valid ? (float)end_new   : 0.0f;
    }

    const float sep = sep_param[0];

    // ---- per-column segment lookup: binary search via ds_bpermute ----
    // lane owns columns j = tile*256 + q*64 + lane  (contiguous per q)
    int  srcc[4];
    float fillv[4];
    bool isdat[4];
    #pragma unroll
    for (int q = 0; q < 4; ++q) {
        const int j = tile * TILE + q * 64 + lane;
        int lo = 0;                                 // invariant: start_new[lo] <= j
        #pragma unroll
        for (int s = 32; s >= 1; s >>= 1) {
            const int mid = lo + s;
            const int sm = __shfl(start_new, mid & 63);
            if (mid < NMAX && sm <= j) lo = mid;
        }
        const int st  = __shfl(start_new, lo);
        const int wd  = __shfl(wv, lo);
        const int sc  = __shfl(s0, lo);
        const int off = j - st;
        isdat[q] = off < wd;                        // data column
        const bool issep = (off == wd) && (lo < nb - 1);  // sep token column
        srcc[q]  = sc + off;                        // in-bounds whenever isdat
        fillv[q] = issep ? sep : 0.0f;              // sep or beyond-tail zero
    }

    // ---- gather 8 rows x 4 col-groups (32 contiguous predicated loads) ----
    const int rbase = rblk * RPB + wave * 8;
    const float* __restrict__ xb = x + (size_t)b * Hn * Wn;
    float* __restrict__ ob = out + (size_t)b * Hn * Wn;

    float v[4][8];
    #pragma unroll
    for (int q = 0; q < 4; ++q) {
        #pragma unroll
        for (int i = 0; i < 8; ++i) {
            const float* __restrict__ rp = xb + (size_t)(rbase + i) * Wn;
            v[q][i] = isdat[q] ? rp[srcc[q]] : fillv[q];
        }
    }
    // ---- 32 plain (cached) contiguous stores: land in L2/L3, not HBM ----
    #pragma unroll
    for (int q = 0; q < 4; ++q) {
        const int j = tile * TILE + q * 64 + lane;
        #pragma unroll
        for (int i = 0; i < 8; ++i) {
            ob[(size_t)(rbase + i) * Wn + j] = v[q][i];
        }
    }
}

extern "C" void kernel_launch(void* const* d_in, const int* in_sizes, int n_in,
                              void* d_out, int out_size, void* d_ws, size_t ws_size,
                              hipStream_t stream) {
    const float* x   = (const float*)d_in[0];
    const int* xi    = (const int*)d_in[1];
    const int* N     = (const int*)d_in[2];
    const float* sep = (const float*)d_in[3];

    float* out_x  = (float*)d_out;
    float* out_xi = (float*)d_out + (size_t)Bn * Hn * Wn;

    dim3 grid(CT * RB, Bn);   // 128 x 16 = 2048 uniform blocks
    pack_tile_kernel<<<grid, 256, 0, stream>>>(x, xi, N, sep, out_x, out_xi);
}

// Round 6
// 114.789 us; speedup vs baseline: 1.1545x; 1.0532x over previous
//
#include <hip/hip_runtime.h>

#define Bn 16
#define Hn 128
#define Wn 8192
#define NMAX 64

// =====================================================================
// Fused row compaction, LDS-packed (R14 = R8 base + cached final stores).
// (R15 resubmit: R14 bench failed on container acquisition — no data.)
// One block per row (2048 blocks, 256 threads = 4 waves).
//  - wave 0: 64-lane width scan; blocks with (row&127)==0 also emit
//    xi_new (as float32) -> no separate xi kernel.
//  - PASS 1: all 32 predicated global loads per thread into registers
//    (full MLP, reads ONLY used columns ~25 MB).
//  - PASS 2: scatter into LDS row image (64-lane contiguous runs ->
//    2-way bank aliasing, free) + sep tokens; zero LDS tail.
//  - FINAL: 8 aligned CACHED float4 stores/thread (R14 change: dropped
//    __builtin_nontemporal_store).
// LEDGER (do not re-attempt):
//  R9:  pair-load PASS1 + tail-bypass stores  -> +2.9us (divergent store).
//  R10: per-segment rect scatter, no LDS      -> 44us kernel (2.1 TB/s).
//  R11: R10 + MLP=32 full-depth loads         -> 40us. MLP not binding.
//  R12: uniform output-tile gather + NT f4    -> 39.5us. occupancy/
//       uniformity not binding.
//  R13: R12 + cached stores + coalesced loads -> 37.9us. store
//       temporality/load coalescing not binding either.
//  => Four no-LDS structures plateau 38-44us vs this LDS structure ~26us;
//     mechanism unconfirmed. Keep the LDS row-image structure.
//  Validated: cached stores leave output dirty in L3 -> harness poison
//  fills run ~3us/fill faster (41.5 vs 44.5); fill kernel proves cached
//  x4 stores sustain 6.4 TB/s, so NT buys nothing kernel-side.
// =====================================================================
__global__ __launch_bounds__(256) void row_pack_lds_kernel(
    const float* __restrict__ x, const int* __restrict__ xi,
    const int* __restrict__ N, const float* __restrict__ sep_param,
    float* __restrict__ out, float* __restrict__ out_xi) {
    __shared__ float s_row[Wn];          // 32 KB row image
    __shared__ int s_start[NMAX];
    __shared__ int s_w[NMAX];
    __shared__ int s_src0[NMAX];
    __shared__ int s_n, s_tail, s_wide;

    const int row = blockIdx.x;          // b*H + h  (C==1)
    const int b   = row >> 7;
    const int tid = threadIdx.x;

    if (tid < NMAX) {                    // wave 0: 64-lane width scan
        int nb = N[b];
        int s0 = xi[(b * NMAX + tid) * 2 + 0];
        int s1 = xi[(b * NMAX + tid) * 2 + 1];
        int w = s1 - s0; if (w < 0) w = 0;
        bool valid = tid < nb;
        int wv = valid ? w : 0;
        int c = wv;
        #pragma unroll
        for (int d = 1; d < 64; d <<= 1) {
            int t = __shfl_up(c, d, 64);
            if (tid >= d) c += t;
        }
        int start_new = c - wv + tid;
        int end_new   = c + tid;
        s_start[tid] = start_new;
        s_w[tid]     = wv;
        s_src0[tid]  = s0;
        unsigned long long wide = __ballot(wv > 127);
        if (tid == 0) {
            s_n = nb;
            s_wide = (wide != 0ULL) ? 1 : 0;
        }
        int last = (nb > 0) ? (nb - 1) : 0;
        if (tid == last) s_tail = (nb > 0) ? end_new : 0;
        if ((row & 127) == 0) {          // fused xi_new (16 writer blocks)
            out_xi[(b * NMAX + tid) * 2 + 0] = valid ? (float)start_new : 0.0f;
            out_xi[(b * NMAX + tid) * 2 + 1] = valid ? (float)end_new : 0.0f;
        }
    }
    __syncthreads();

    const int nb   = s_n;
    const int tail = s_tail;
    const float sep = sep_param[0];
    const float* __restrict__ xrow = x + (size_t)row * Wn;
    float* __restrict__ orow = out + (size_t)row * Wn;
    const int wave = tid >> 6;
    const int lane = tid & 63;

    // ---- PASS 1: issue ALL global loads (independent, predicated) ----
    float v0[16], v1[16];
    int sg_s[16], sg_wt[16];
    #pragma unroll
    for (int k = 0; k < 16; ++k) {
        const int seg = wave + 4 * k;
        const bool act = seg < nb;
        const int s    = act ? s_start[seg] : 0;
        const int w    = act ? s_w[seg] : 0;
        const int src0 = act ? s_src0[seg] : 0;
        sg_s[k]  = s;
        sg_wt[k] = act ? (w + ((seg < nb - 1) ? 1 : 0)) : 0;
        v0[k] = (lane < w)      ? xrow[src0 + lane]      : sep;
        v1[k] = (lane + 64 < w) ? xrow[src0 + lane + 64] : sep;
    }

    // ---- PASS 2: scatter into LDS row image (2-way aliasing = free) ----
    #pragma unroll
    for (int k = 0; k < 16; ++k) {
        if (lane < sg_wt[k])      s_row[sg_s[k] + lane]      = v0[k];
        if (lane + 64 < sg_wt[k]) s_row[sg_s[k] + lane + 64] = v1[k];
    }

    // ---- rare fallback for segments wider than 128 (never in practice) ----
    if (s_wide) {
        for (int seg = wave; seg < nb; seg += 4) {
            const int w = s_w[seg];
            const int wtot = w + ((seg < nb - 1) ? 1 : 0);
            for (int l = 128 + lane; l < wtot; l += 64) {
                s_row[s_start[seg] + l] = (l < w) ? xrow[s_src0[seg] + l] : sep;
            }
        }
    }

    // ---- zero LDS tail [tail, Wn): scalar to 16B alignment, then b128 ----
    const int t4 = (tail + 3) & ~3;
    if (tid < (t4 - tail)) s_row[tail + tid] = 0.0f;    // <=3 threads
    float4* s_row4 = reinterpret_cast<float4*>(s_row);
    const float4 z4 = make_float4(0.0f, 0.0f, 0.0f, 0.0f);
    for (int i4 = (t4 >> 2) + tid; i4 < (Wn >> 2); i4 += 256) {
        s_row4[i4] = z4;
    }
    __syncthreads();

    // ---- FINAL: aligned CACHED float4 row store (R14: no nontemporal) ----
    float4* orow4 = reinterpret_cast<float4*>(orow);
    #pragma unroll
    for (int g = 0; g < 8; ++g) {
        orow4[g * 256 + tid] = s_row4[g * 256 + tid];
    }
}

extern "C" void kernel_launch(void* const* d_in, const int* in_sizes, int n_in,
                              void* d_out, int out_size, void* d_ws, size_t ws_size,
                              hipStream_t stream) {
    const float* x   = (const float*)d_in[0];
    const int* xi    = (const int*)d_in[1];
    const int* N     = (const int*)d_in[2];
    const float* sep = (const float*)d_in[3];

    float* out_x  = (float*)d_out;
    float* out_xi = (float*)d_out + (size_t)Bn * Hn * Wn;

    row_pack_lds_kernel<<<Bn * Hn, 256, 0, stream>>>(x, xi, N, sep, out_x, out_xi);
}